// Round 10
// baseline (475.624 us; speedup 1.0000x reference)
//
#include <hip/hip_runtime.h>
#include <cstdint>

#define NN 100000
#define EE 1600000
#define ET (EE + NN)
#define NBUCK 782            // ceil(NN/128), 128 nodes per bucket
#define BCAP 3584            // fixed per-bucket staging capacity (mean ~2176, sd ~47)
#define G_GEMM 1563          // gemm blocks in fused launch
#define G_FILL 256           // bin_fill blocks
#define G_WPREP 80           // wprep blocks (16384+4096 = 20480 elems / 256)

typedef unsigned int u32;
typedef unsigned short u16;
typedef short bf16x8 __attribute__((ext_vector_type(8)));
typedef float f32x4 __attribute__((ext_vector_type(4)));

__device__ __forceinline__ u16 f2bf(float f) {
    union { float f; u32 i; } v; v.f = f;
    u32 r = v.i + 0x7FFFu + ((v.i >> 16) & 1u);
    return (u16)(r >> 16);
}
__device__ __forceinline__ float bf_lo(u32 u) {   // low bf16 -> f32
    union { u32 i; float f; } v; v.i = u << 16; return v.f;
}
__device__ __forceinline__ float bf_hi(u32 u) {   // high bf16 -> f32
    union { u32 i; float f; } v; v.i = u & 0xffff0000u; return v.f;
}
__device__ __forceinline__ void get_edge(const int* __restrict__ ei, int e, int& s, int& d) {
    if (e < EE) { s = ei[e]; d = ei[EE + e]; }
    else { s = e - EE; d = s; }
}
__device__ __forceinline__ float leaky(float x) { return x > 0.f ? x : 0.2f * x; }

// ---------------- MFMA GEMM body + fused attn epilogue.
// 64 rows x OUTC, 256 thr. bf16 MFMA 16x16x32, fp32 acc.
// A[m=lane&15][k=q*8+j], B[n=lane&15][k=q*8+j], C/D col=lane&15 row=q*4+reg.
// WCVT: stage W from fp32 [k][OUTC] (converted in-kernel); else bf16 [c][k] u32-packed.
template<int OUTC, bool IN16, bool WCVT>
__device__ __forceinline__ void gemm_body(int r0, u32* lds,
    const void* __restrict__ Xv, const void* __restrict__ Wsrc,
    const float* __restrict__ asw, const float* __restrict__ adw,
    u16* __restrict__ Hout16, float* __restrict__ as_o, float* __restrict__ ad_o, int tid)
{
    constexpr int NT = OUTC / 16;
    constexpr int HS = (OUTC == 128) ? 132 : 36;
    u32* wl = lds + 64 * 68;

    if (IN16) {
        const u32* Xg = (const u32*)Xv;
        for (int i = tid; i < 64 * 64; i += 256) {
            int r = i >> 6, k2 = i & 63;
            u32 v = 0;
            if (r0 + r < NN) v = Xg[(size_t)(r0 + r) * 64 + k2];
            lds[r * 68 + k2] = v;
        }
    } else {
        const float* Xf = (const float*)Xv;
        for (int i = tid; i < 64 * 64; i += 256) {
            int r = i >> 6, k2 = i & 63;
            u32 v = 0;
            if (r0 + r < NN) {
                float2 f = *(const float2*)(Xf + (size_t)(r0 + r) * 128 + k2 * 2);
                v = (u32)f2bf(f.x) | ((u32)f2bf(f.y) << 16);
            }
            lds[r * 68 + k2] = v;
        }
    }
    if (WCVT) {       // fp32 [k][OUTC] -> bf16-pair [c][k2], OUTC=128
        const float* Wf = (const float*)Wsrc;
        for (int i = tid; i < 128 * 64; i += 256) {
            int c = i & 127, k2 = i >> 7;
            float f0 = Wf[(2 * k2) * 128 + c];
            float f1 = Wf[(2 * k2 + 1) * 128 + c];
            wl[c * 68 + k2] = (u32)f2bf(f0) | ((u32)f2bf(f1) << 16);
        }
    } else {
        const u32* Wg = (const u32*)Wsrc;
        for (int i = tid; i < OUTC * 64; i += 256) {
            int c = i >> 6, k2 = i & 63;
            wl[c * 68 + k2] = Wg[i];
        }
    }
    __syncthreads();

    const int w = tid >> 6, l = tid & 63;
    const int lm = l & 15, q = l >> 4;

    f32x4 acc[NT];
    #pragma unroll
    for (int T = 0; T < NT; T++)
        #pragma unroll
        for (int r = 0; r < 4; r++) acc[T][r] = 0.f;

    #pragma unroll
    for (int kc = 0; kc < 4; kc++) {
        bf16x8 af = *(const bf16x8*)&lds[(16 * w + lm) * 68 + kc * 16 + q * 4];
        #pragma unroll
        for (int T = 0; T < NT; T++) {
            bf16x8 bfr = *(const bf16x8*)&wl[(16 * T + lm) * 68 + kc * 16 + q * 4];
            acc[T] = __builtin_amdgcn_mfma_f32_16x16x32_bf16(af, bfr, acc[T], 0, 0, 0);
        }
    }
    __syncthreads();

    float* hl = (float*)lds;
    #pragma unroll
    for (int T = 0; T < NT; T++)
        #pragma unroll
        for (int rg = 0; rg < 4; rg++)
            hl[(16 * w + q * 4 + rg) * HS + 16 * T + lm] = acc[T][rg];
    __syncthreads();

    for (int i = tid; i < 64 * (OUTC / 2); i += 256) {
        int r = i / (OUTC / 2), k2 = i % (OUTC / 2);
        int row = r0 + r;
        if (row < NN) {
            float a = hl[r * HS + k2 * 2];
            float b = hl[r * HS + k2 * 2 + 1];
            ((u32*)Hout16)[(size_t)row * (OUTC / 2) + k2] = (u32)f2bf(a) | ((u32)f2bf(b) << 16);
        }
    }
    if (OUTC == 128) {
        const int row = tid >> 2, part = tid & 3;
        const float* hp = &hl[row * HS + part * 32];
        const float* aw = asw + part * 32;
        const float* dw = adw + part * 32;
        float s = 0.f, d = 0.f;
        #pragma unroll
        for (int c = 0; c < 32; c++) { float hv = hp[c]; s += hv * aw[c]; d += hv * dw[c]; }
        const int grow = r0 + row;
        if (grow < NN) { as_o[(size_t)grow * 4 + part] = s; ad_o[(size_t)grow * 4 + part] = d; }
    } else {
        if (tid < 64) {
            const float* hp = &hl[tid * HS];
            float s = 0.f, d = 0.f;
            #pragma unroll
            for (int c = 0; c < 32; c++) { float hv = hp[c]; s += hv * asw[c]; d += hv * adw[c]; }
            const int grow = r0 + tid;
            if (grow < NN) { as_o[grow] = s; ad_o[grow] = d; }
        }
    }
}

// ---------------- bin_fill body (bucketed staging, fixed capacity)
__device__ __forceinline__ void bin_fill_body(int bid, int* hist, int* base,
    const int* __restrict__ ei, int* __restrict__ gcur, u32* __restrict__ pairs, int t)
{
    for (int i = t; i < NBUCK; i += 256) hist[i] = 0;
    __syncthreads();
    const int chunk = (ET + G_FILL - 1) / G_FILL;
    const int e0 = bid * chunk;
    const int e1 = min(e0 + chunk, ET);
    for (int e = e0 + t; e < e1; e += 256) {
        int s, d; get_edge(ei, e, s, d);
        atomicAdd(&hist[d >> 7], 1);
    }
    __syncthreads();
    for (int i = t; i < NBUCK; i += 256) {
        int c = hist[i];
        base[i] = c ? atomicAdd(&gcur[i], c) : 0;
        hist[i] = 0;
    }
    __syncthreads();
    for (int e = e0 + t; e < e1; e += 256) {
        int s, d; get_edge(ei, e, s, d);
        int b = d >> 7;
        int pos = atomicAdd(&hist[b], 1);
        pairs[(size_t)b * BCAP + base[b] + pos] = ((u32)(d & 127) << 25) | (u32)s;
    }
}

// ---------------- fused front end: gemm layer1 | bin_fill | wprep(wt2,wt3)
__global__ __launch_bounds__(256) void fused1_kernel(
    const float* __restrict__ X, const float* __restrict__ W1,
    const float* __restrict__ as1, const float* __restrict__ ad1,
    u16* __restrict__ hb16, float* __restrict__ asb, float* __restrict__ adb,
    const int* __restrict__ ei, int* __restrict__ gcur, u32* __restrict__ pairs,
    const float* __restrict__ W2, const float* __restrict__ W3,
    u16* __restrict__ wt2, u16* __restrict__ wt3)
{
    __shared__ __align__(16) u32 smem[13056];
    const int bid = blockIdx.x;
    const int tid = threadIdx.x;
    if (bid < G_GEMM) {
        gemm_body<128, false, true>(bid * 64, smem, X, W1, as1, ad1, hb16, asb, adb, tid);
    } else if (bid < G_GEMM + G_FILL) {
        int* hist = (int*)smem;
        bin_fill_body(bid - G_GEMM, hist, hist + NBUCK, ei, gcur, pairs, tid);
    } else {
        int i = (bid - G_GEMM - G_FILL) * 256 + tid;
        if (i < 16384)      { int c = i >> 7, k = i & 127; wt2[i] = f2bf(W2[k * 128 + c]); }
        else                { int j = i - 16384; int c = j >> 7, k = j & 127; wt3[j] = f2bf(W3[k * 32 + c]); }
    }
}

// ---------------- standalone MFMA GEMM (layers 2/3, bf16 in, pre-converted W)
template<int OUTC>
__global__ __launch_bounds__(256) void gemm_mfma(
    const void* __restrict__ Xv, const u16* __restrict__ Wt16g,
    const float* __restrict__ asw, const float* __restrict__ adw,
    u16* __restrict__ Hout16, float* __restrict__ as_o, float* __restrict__ ad_o)
{
    constexpr int LDSU = (OUTC == 128) ? 13056 : 6528;
    __shared__ __align__(16) u32 lds[LDSU];
    gemm_body<OUTC, true, false>(blockIdx.x * 64, lds, Xv, Wt16g, asw, adw,
                                 Hout16, as_o, ad_o, threadIdx.x);
}

// ---------------- CSR finalize (unchanged)
__global__ __launch_bounds__(1024) void bscan_kernel(const int* __restrict__ bcnt,
    int* __restrict__ bbase, int* __restrict__ rowp)
{
    __shared__ int lds[1024];
    const int t = threadIdx.x;
    int v = (t < NBUCK) ? bcnt[t] : 0;
    lds[t] = v;
    __syncthreads();
    for (int off = 1; off < 1024; off <<= 1) {
        int x = (t >= off) ? lds[t - off] : 0;
        __syncthreads();
        lds[t] += x;
        __syncthreads();
    }
    if (t < NBUCK) bbase[t] = lds[t] - v;
    if (t == 0) { bbase[NBUCK] = ET; rowp[NN] = ET; }
}

__global__ __launch_bounds__(256) void bucket_csr_kernel(const u32* __restrict__ pairs,
    const int* __restrict__ bcnt, const int* __restrict__ bbase,
    int* __restrict__ rowp, int* __restrict__ col)
{
    __shared__ int hist[128], scn[128];
    __shared__ int col_lds[BCAP];
    const int b = blockIdx.x;
    const int cbase = bbase[b];
    const int cnt = bcnt[b];
    const u32* pk0 = pairs + (size_t)b * BCAP;
    const int t = threadIdx.x;
    if (t < 128) hist[t] = 0;
    __syncthreads();
    for (int i = t; i < cnt; i += 256)
        atomicAdd(&hist[pk0[i] >> 25], 1);
    __syncthreads();
    if (t < 128) scn[t] = hist[t];
    __syncthreads();
    for (int off = 1; off < 128; off <<= 1) {
        int x = (t < 128 && t >= off) ? scn[t - off] : 0;
        __syncthreads();
        if (t < 128) scn[t] += x;
        __syncthreads();
    }
    if (t < 128) {
        int ex = scn[t] - hist[t];
        int node = b * 128 + t;
        if (node < NN) rowp[node] = cbase + ex;
        hist[t] = ex;
    }
    __syncthreads();
    for (int i = t; i < cnt; i += 256) {
        u32 pk = pk0[i];
        int pos = atomicAdd(&hist[pk >> 25], 1);
        if (pos < BCAP) col_lds[pos] = pk & 0x1FFFFFFu;
    }
    __syncthreads();
    for (int i = t; i < cnt; i += 256)
        col[cbase + i] = col_lds[i];
}

// ---------------- grouped fused aggregation, H=4: 16 lanes per node, 4 nodes/wave.
// Lane sub owns 8 channels [8*sub, 8*sub+8) (all in head sub>>2); gather load is
// uint4 (16 B/lane, 1 KB/wave-inst = 4 rows). p/soff exchanged via per-wave LDS.
template<bool DOELU>
__global__ __launch_bounds__(256) void agg4g_kernel(
    const int* __restrict__ rowp, const int* __restrict__ col,
    const float* __restrict__ as_, const float* __restrict__ ad_,
    const u16* __restrict__ Hb16, const float* __restrict__ bias,
    u16* __restrict__ outp16)
{
    __shared__ float pex[4 * 288];       // [wave][group(stride 68)][edge*4 + head]
    __shared__ u32   sex[4 * 64];        // [wave][group*16 + edge] row byte offsets
    const int tid = threadIdx.x;
    const int wv = tid >> 6;
    const int lane = tid & 63;
    const int g = lane >> 4;
    const int sub = lane & 15;
    const int H = sub >> 2;              // head of this lane's channels
    const int node = blockIdx.x * 16 + wv * 4 + g;

    const int start = rowp[node];
    const int end   = rowp[node + 1];
    const float4 ad4 = ((const float4*)ad_)[node];
    const float4* as4 = (const float4*)as_;
    float* pb = &pex[wv * 288 + g * 68];
    u32*   sb = &sex[wv * 64 + g * 16];
    const char* hbase = (const char*)Hb16 + sub * 16;

    float m0 = -1e30f, m1 = -1e30f, m2 = -1e30f, m3 = -1e30f;
    float d0 = 0.f, d1 = 0.f, d2 = 0.f, d3 = 0.f;
    float a[8];
    #pragma unroll
    for (int i = 0; i < 8; i++) a[i] = 0.f;

    for (int j0 = start; j0 < end; j0 += 16) {
        const int j = j0 + sub;
        const bool valid = (j < end);
        const int s = valid ? col[j] : 0;
        const float4 av = as4[s];
        float l0 = valid ? leaky(av.x + ad4.x) : -1e30f;
        float l1 = valid ? leaky(av.y + ad4.y) : -1e30f;
        float l2 = valid ? leaky(av.z + ad4.z) : -1e30f;
        float l3 = valid ? leaky(av.w + ad4.w) : -1e30f;
        float c0 = l0, c1 = l1, c2 = l2, c3 = l3;
        #pragma unroll
        for (int off = 8; off; off >>= 1) {
            c0 = fmaxf(c0, __shfl_xor(c0, off, 16));
            c1 = fmaxf(c1, __shfl_xor(c1, off, 16));
            c2 = fmaxf(c2, __shfl_xor(c2, off, 16));
            c3 = fmaxf(c3, __shfl_xor(c3, off, 16));
        }
        const float n0 = fmaxf(m0, c0), n1 = fmaxf(m1, c1);
        const float n2 = fmaxf(m2, c2), n3 = fmaxf(m3, c3);
        const float s0 = __expf(m0 - n0), s1 = __expf(m1 - n1);
        const float s2 = __expf(m2 - n2), s3 = __expf(m3 - n3);
        float p0 = valid ? __expf(l0 - n0) : 0.f;
        float p1 = valid ? __expf(l1 - n1) : 0.f;
        float p2 = valid ? __expf(l2 - n2) : 0.f;
        float p3 = valid ? __expf(l3 - n3) : 0.f;
        float q0 = p0, q1 = p1, q2 = p2, q3 = p3;
        #pragma unroll
        for (int off = 8; off; off >>= 1) {
            q0 += __shfl_xor(q0, off, 16);
            q1 += __shfl_xor(q1, off, 16);
            q2 += __shfl_xor(q2, off, 16);
            q3 += __shfl_xor(q3, off, 16);
        }
        d0 = d0 * s0 + q0; d1 = d1 * s1 + q1;
        d2 = d2 * s2 + q2; d3 = d3 * s3 + q3;
        m0 = n0; m1 = n1; m2 = n2; m3 = n3;
        const float scH = (H == 0) ? s0 : (H == 1) ? s1 : (H == 2) ? s2 : s3;
        #pragma unroll
        for (int i = 0; i < 8; i++) a[i] *= scH;
        // exchange p (per head) and row offsets via LDS (wave-private, no barrier)
        pb[sub * 4 + 0] = p0; pb[sub * 4 + 1] = p1;
        pb[sub * 4 + 2] = p2; pb[sub * 4 + 3] = p3;
        sb[sub] = (u32)s << 8;
        u32 so[16]; float pi[16];
        #pragma unroll
        for (int i = 0; i < 16; i++) { so[i] = sb[i]; pi[i] = pb[i * 4 + H]; }
        #pragma unroll
        for (int i = 0; i < 16; i++) {
            const uint4 w = *(const uint4*)(hbase + so[i]);
            a[0] += pi[i] * bf_lo(w.x); a[1] += pi[i] * bf_hi(w.x);
            a[2] += pi[i] * bf_lo(w.y); a[3] += pi[i] * bf_hi(w.y);
            a[4] += pi[i] * bf_lo(w.z); a[5] += pi[i] * bf_hi(w.z);
            a[6] += pi[i] * bf_lo(w.w); a[7] += pi[i] * bf_hi(w.w);
        }
    }
    const float denH = (H == 0) ? d0 : (H == 1) ? d1 : (H == 2) ? d2 : d3;
    const float r = 1.f / (denH + 1e-16f);
    const float4 b0 = ((const float4*)bias)[sub * 2];
    const float4 b1 = ((const float4*)bias)[sub * 2 + 1];
    float v[8];
    v[0] = a[0] * r + b0.x; v[1] = a[1] * r + b0.y;
    v[2] = a[2] * r + b0.z; v[3] = a[3] * r + b0.w;
    v[4] = a[4] * r + b1.x; v[5] = a[5] * r + b1.y;
    v[6] = a[6] * r + b1.z; v[7] = a[7] * r + b1.w;
    if (DOELU) {
        #pragma unroll
        for (int i = 0; i < 8; i++) v[i] = v[i] > 0.f ? v[i] : (__expf(v[i]) - 1.f);
    }
    uint4 o;
    o.x = (u32)f2bf(v[0]) | ((u32)f2bf(v[1]) << 16);
    o.y = (u32)f2bf(v[2]) | ((u32)f2bf(v[3]) << 16);
    o.z = (u32)f2bf(v[4]) | ((u32)f2bf(v[5]) << 16);
    o.w = (u32)f2bf(v[6]) | ((u32)f2bf(v[7]) << 16);
    *(uint4*)(outp16 + (size_t)node * 128 + sub * 8) = o;
}

// ---------------- H=1 (F=32): 32 lanes/node, 32-edge chunks, always-pipelined.
__global__ __launch_bounds__(256) void agg1_kernel(
    const int* __restrict__ rowp, const int* __restrict__ col,
    const float* __restrict__ as_, const float* __restrict__ ad_,
    const u16* __restrict__ Hb16, const float* __restrict__ bias,
    float* __restrict__ outp)
{
    const int t = threadIdx.x;
    const int lane = t & 31;
    const int node = blockIdx.x * 8 + (t >> 5);

    const int start = rowp[node];
    const int end   = rowp[node + 1];
    const float adv = ad_[node];
    const char* hbase = (const char*)Hb16 + lane * 2;
    const float bvv = bias[lane];

    float m = -1e30f, den = 0.f, acc = 0.f;
    for (int j0 = start; j0 < end; j0 += 32) {
        const int j = j0 + lane;
        const bool valid = (j < end);
        const int s = valid ? col[j] : 0;
        const float lg = valid ? leaky(as_[s] + adv) : -1e30f;
        float cm = lg;
        #pragma unroll
        for (int off = 16; off; off >>= 1) cm = fmaxf(cm, __shfl_xor(cm, off, 32));
        const float mnew = fmaxf(m, cm);
        const float sc = __expf(m - mnew);
        acc *= sc; den *= sc; m = mnew;
        const float p = valid ? __expf(lg - m) : 0.f;
        float ps = p;
        #pragma unroll
        for (int off = 16; off; off >>= 1) ps += __shfl_xor(ps, off, 32);
        den += ps;
        const int soff = s << 6;
        int so[32]; float pi[32];
        #pragma unroll
        for (int i = 0; i < 32; i++) {
            so[i] = __shfl(soff, i, 32);
            pi[i] = __shfl(p, i, 32);
        }
        #pragma unroll
        for (int i = 0; i < 32; i++)
            acc += pi[i] * bf_lo((u32)*(const u16*)(hbase + so[i]));
    }
    outp[(size_t)node * 32 + lane] = acc / (den + 1e-16f) + bvv;
}

extern "C" void kernel_launch(void* const* d_in, const int* in_sizes, int n_in,
                              void* d_out, int out_size, void* d_ws, size_t ws_size,
                              hipStream_t stream)
{
    const float* x   = (const float*)d_in[0];
    const int*   ei  = (const int*)d_in[1];
    const float* W1  = (const float*)d_in[2];
    const float* as1 = (const float*)d_in[3];
    const float* ad1 = (const float*)d_in[4];
    const float* b1  = (const float*)d_in[5];
    const float* W2  = (const float*)d_in[6];
    const float* as2 = (const float*)d_in[7];
    const float* ad2 = (const float*)d_in[8];
    const float* b2  = (const float*)d_in[9];
    const float* W3  = (const float*)d_in[10];
    const float* as3 = (const float*)d_in[11];
    const float* ad3 = (const float*)d_in[12];
    const float* b3  = (const float*)d_in[13];
    float* outp = (float*)d_out;

    char* ws = (char*)d_ws;
    u16*   hb16  = (u16*)(ws);                    // N*128 bf16 = 25.6 MB (gather source)
    u16*   xb16  = (u16*)(ws + 25700000);         // N*128 bf16 = 25.6 MB (layer input)
    u16*   h3b16 = (u16*)(ws + 51400000);         // N*32 bf16 = 6.4 MB
    float* asb   = (float*)(ws + 57900000);       // N*4 f32
    float* adb   = (float*)(ws + 59500000);       // N*4 f32
    int*   rowp  = (int*)(ws + 61100000);         // N+1 ints
    int*   col   = (int*)(ws + 61600000);         // ET ints = 6.8 MB
    u32*   pairs = (u32*)(ws + 68400032);         // NBUCK*BCAP u32 = 11.2 MB
    int*   gcur  = (int*)(ws + 79700000);         // NBUCK ints (counts after fill)
    int*   bbase = (int*)(ws + 79704096);         // NBUCK+1 ints
    u16*   wt2   = (u16*)(ws + 79750000);         // 128x128 bf16 = 32 KB
    u16*   wt3   = (u16*)(ws + 79790000);         // 32x128 bf16 = 8 KB -> ~79.8 MB total

    const dim3 B(256);
    const int gG = (NN + 63) / 64;   // 1563

    // ---------------- fused front end: gemm1 (+inline W1 cvt) | bin_fill | wprep
    hipMemsetAsync(gcur, 0, NBUCK * 4, stream);
    fused1_kernel<<<G_GEMM + G_FILL + G_WPREP, B, 0, stream>>>(
        x, W1, as1, ad1, hb16, asb, adb, ei, gcur, pairs, W2, W3, wt2, wt3);
    bscan_kernel<<<1, dim3(1024), 0, stream>>>(gcur, bbase, rowp);
    bucket_csr_kernel<<<NBUCK, B, 0, stream>>>(pairs, gcur, bbase, rowp, col);

    // ---------------- layer 1 aggregation (H=4)
    agg4g_kernel<true><<<NN / 16, B, 0, stream>>>(rowp, col, asb, adb, hb16, b1, xb16);

    // ---------------- layer 2 (H=4)
    gemm_mfma<128><<<gG, B, 0, stream>>>(xb16, wt2, as2, ad2, hb16, asb, adb);
    agg4g_kernel<true><<<NN / 16, B, 0, stream>>>(rowp, col, asb, adb, hb16, b2, xb16);

    // ---------------- layer 3 (H=1, C=32)
    gemm_mfma<32><<<gG, B, 0, stream>>>(xb16, wt3, as3, ad3, h3b16, asb, adb);
    agg1_kernel<<<NN / 8, B, 0, stream>>>(rowp, col, asb, adb, h3b16, b3, outp);
}

// Round 11
// 462.566 us; speedup vs baseline: 1.0282x; 1.0282x over previous
//
#include <hip/hip_runtime.h>
#include <cstdint>

#define NN 100000
#define EE 1600000
#define ET (EE + NN)
#define NBUCK 782            // ceil(NN/128), 128 nodes per bucket
#define BCAP 3584            // fixed per-bucket staging capacity (mean ~2176, sd ~47)
#define G_FILL 128           // bin_fill blocks (bigger chunks -> longer runs per bucket)

typedef unsigned int u32;
typedef unsigned short u16;
typedef short bf16x8 __attribute__((ext_vector_type(8)));
typedef float f32x4 __attribute__((ext_vector_type(4)));

__device__ __forceinline__ u16 f2bf(float f) {
    union { float f; u32 i; } v; v.f = f;
    u32 r = v.i + 0x7FFFu + ((v.i >> 16) & 1u);
    return (u16)(r >> 16);
}
__device__ __forceinline__ float bf_lo(u32 u) {
    union { u32 i; float f; } v; v.i = u << 16; return v.f;
}
__device__ __forceinline__ float bf_hi(u32 u) {
    union { u32 i; float f; } v; v.i = u & 0xffff0000u; return v.f;
}
__device__ __forceinline__ void get_edge(const int* __restrict__ ei, int e, int& s, int& d) {
    if (e < EE) { s = ei[e]; d = ei[EE + e]; }
    else { s = e - EE; d = s; }
}
__device__ __forceinline__ float leaky(float x) { return x > 0.f ? x : 0.2f * x; }

// ---------------- W prep: fp32 [k][c] -> bf16 transposed [c][k] (one-time, tiny)
__global__ __launch_bounds__(256) void wprep_kernel(
    const float* __restrict__ W1, const float* __restrict__ W2, const float* __restrict__ W3,
    u16* __restrict__ wt1, u16* __restrict__ wt2, u16* __restrict__ wt3)
{
    int i = blockIdx.x * 256 + threadIdx.x;
    if (i < 16384)      { int c = i >> 7, k = i & 127; wt1[i] = f2bf(W1[k * 128 + c]); }
    else if (i < 32768) { int j = i - 16384; int c = j >> 7, k = j & 127; wt2[j] = f2bf(W2[k * 128 + c]); }
    else if (i < 36864) { int j = i - 32768; int c = j >> 7, k = j & 127; wt3[j] = f2bf(W3[k * 32 + c]); }
}

// ---------------- MFMA GEMM + fused attn epilogue (64 rows x OUTC, 256 thr)
// A[m=lane&15][k=q*8+j], B[n=lane&15][k=q*8+j], C/D col=lane&15 row=q*4+reg.
template<int OUTC, bool IN16>
__global__ __launch_bounds__(256) void gemm_mfma(
    const void* __restrict__ Xv, const u16* __restrict__ Wt16g,
    const float* __restrict__ asw, const float* __restrict__ adw,
    u16* __restrict__ Hout16, float* __restrict__ as_o, float* __restrict__ ad_o)
{
    constexpr int NT = OUTC / 16;
    constexpr int LDSU = (OUTC == 128) ? 13056 : 6528;
    constexpr int HS = (OUTC == 128) ? 132 : 36;
    __shared__ __align__(16) u32 lds[LDSU];
    u32* wl = lds + 64 * 68;

    const int tid = threadIdx.x;
    const int r0 = blockIdx.x * 64;

    if (IN16) {
        const u32* Xg = (const u32*)Xv;
        for (int i = tid; i < 64 * 64; i += 256) {
            int r = i >> 6, k2 = i & 63;
            u32 v = 0;
            if (r0 + r < NN) v = Xg[(size_t)(r0 + r) * 64 + k2];
            lds[r * 68 + k2] = v;
        }
    } else {
        const float* Xf = (const float*)Xv;
        for (int i = tid; i < 64 * 64; i += 256) {
            int r = i >> 6, k2 = i & 63;
            u32 v = 0;
            if (r0 + r < NN) {
                float2 f = *(const float2*)(Xf + (size_t)(r0 + r) * 128 + k2 * 2);
                v = (u32)f2bf(f.x) | ((u32)f2bf(f.y) << 16);
            }
            lds[r * 68 + k2] = v;
        }
    }
    {
        const u32* Wg = (const u32*)Wt16g;
        for (int i = tid; i < OUTC * 64; i += 256) {
            int c = i >> 6, k2 = i & 63;
            wl[c * 68 + k2] = Wg[i];
        }
    }
    __syncthreads();

    const int w = tid >> 6, l = tid & 63;
    const int lm = l & 15, q = l >> 4;

    f32x4 acc[NT];
    #pragma unroll
    for (int T = 0; T < NT; T++)
        #pragma unroll
        for (int r = 0; r < 4; r++) acc[T][r] = 0.f;

    #pragma unroll
    for (int kc = 0; kc < 4; kc++) {
        bf16x8 af = *(const bf16x8*)&lds[(16 * w + lm) * 68 + kc * 16 + q * 4];
        #pragma unroll
        for (int T = 0; T < NT; T++) {
            bf16x8 bfr = *(const bf16x8*)&wl[(16 * T + lm) * 68 + kc * 16 + q * 4];
            acc[T] = __builtin_amdgcn_mfma_f32_16x16x32_bf16(af, bfr, acc[T], 0, 0, 0);
        }
    }
    __syncthreads();

    float* hl = (float*)lds;
    #pragma unroll
    for (int T = 0; T < NT; T++)
        #pragma unroll
        for (int rg = 0; rg < 4; rg++)
            hl[(16 * w + q * 4 + rg) * HS + 16 * T + lm] = acc[T][rg];
    __syncthreads();

    for (int i = tid; i < 64 * (OUTC / 2); i += 256) {
        int r = i / (OUTC / 2), k2 = i % (OUTC / 2);
        int row = r0 + r;
        if (row < NN) {
            float a = hl[r * HS + k2 * 2];
            float b = hl[r * HS + k2 * 2 + 1];
            ((u32*)Hout16)[(size_t)row * (OUTC / 2) + k2] = (u32)f2bf(a) | ((u32)f2bf(b) << 16);
        }
    }
    if (OUTC == 128) {
        const int row = tid >> 2, part = tid & 3;
        const float* hp = &hl[row * HS + part * 32];
        const float* aw = asw + part * 32;
        const float* dw = adw + part * 32;
        float s = 0.f, d = 0.f;
        #pragma unroll
        for (int c = 0; c < 32; c++) { float hv = hp[c]; s += hv * aw[c]; d += hv * dw[c]; }
        const int grow = r0 + row;
        if (grow < NN) { as_o[(size_t)grow * 4 + part] = s; ad_o[(size_t)grow * 4 + part] = d; }
    } else {
        if (tid < 64) {
            const float* hp = &hl[tid * HS];
            float s = 0.f, d = 0.f;
            #pragma unroll
            for (int c = 0; c < 32; c++) { float hv = hp[c]; s += hv * asw[c]; d += hv * adw[c]; }
            const int grow = r0 + tid;
            if (grow < NN) { as_o[grow] = s; ad_o[grow] = d; }
        }
    }
}

// ---------------- bucketed CSR build (standalone, small LDS, high occupancy)
__global__ __launch_bounds__(256) void bin_fill_kernel(const int* __restrict__ ei,
    int* __restrict__ gcur, u32* __restrict__ pairs)
{
    __shared__ int hist[NBUCK];
    __shared__ int base[NBUCK];
    const int t = threadIdx.x;
    for (int i = t; i < NBUCK; i += 256) hist[i] = 0;
    __syncthreads();
    const int chunk = (ET + G_FILL - 1) / G_FILL;
    const int e0 = blockIdx.x * chunk;
    const int e1 = min(e0 + chunk, ET);
    for (int e = e0 + t; e < e1; e += 256) {
        int s, d; get_edge(ei, e, s, d);
        atomicAdd(&hist[d >> 7], 1);
    }
    __syncthreads();
    for (int i = t; i < NBUCK; i += 256) {
        int c = hist[i];
        base[i] = c ? atomicAdd(&gcur[i], c) : 0;
        hist[i] = 0;
    }
    __syncthreads();
    for (int e = e0 + t; e < e1; e += 256) {
        int s, d; get_edge(ei, e, s, d);
        int b = d >> 7;
        int pos = atomicAdd(&hist[b], 1);
        pairs[(size_t)b * BCAP + base[b] + pos] = ((u32)(d & 127) << 25) | (u32)s;
    }
}

__global__ __launch_bounds__(1024) void bscan_kernel(const int* __restrict__ bcnt,
    int* __restrict__ bbase, int* __restrict__ rowp)
{
    __shared__ int lds[1024];
    const int t = threadIdx.x;
    int v = (t < NBUCK) ? bcnt[t] : 0;
    lds[t] = v;
    __syncthreads();
    for (int off = 1; off < 1024; off <<= 1) {
        int x = (t >= off) ? lds[t - off] : 0;
        __syncthreads();
        lds[t] += x;
        __syncthreads();
    }
    if (t < NBUCK) bbase[t] = lds[t] - v;
    if (t == 0) { bbase[NBUCK] = ET; rowp[NN] = ET; }
}

__global__ __launch_bounds__(256) void bucket_csr_kernel(const u32* __restrict__ pairs,
    const int* __restrict__ bcnt, const int* __restrict__ bbase,
    int* __restrict__ rowp, int* __restrict__ col)
{
    __shared__ int hist[128], scn[128];
    __shared__ int col_lds[BCAP];
    const int b = blockIdx.x;
    const int cbase = bbase[b];
    const int cnt = bcnt[b];
    const u32* pk0 = pairs + (size_t)b * BCAP;
    const int t = threadIdx.x;
    if (t < 128) hist[t] = 0;
    __syncthreads();
    for (int i = t; i < cnt; i += 256)
        atomicAdd(&hist[pk0[i] >> 25], 1);
    __syncthreads();
    if (t < 128) scn[t] = hist[t];
    __syncthreads();
    for (int off = 1; off < 128; off <<= 1) {
        int x = (t < 128 && t >= off) ? scn[t - off] : 0;
        __syncthreads();
        if (t < 128) scn[t] += x;
        __syncthreads();
    }
    if (t < 128) {
        int ex = scn[t] - hist[t];
        int node = b * 128 + t;
        if (node < NN) rowp[node] = cbase + ex;
        hist[t] = ex;
    }
    __syncthreads();
    for (int i = t; i < cnt; i += 256) {
        u32 pk = pk0[i];
        int pos = atomicAdd(&hist[pk >> 25], 1);
        if (pos < BCAP) col_lds[pos] = pk & 0x1FFFFFFu;
    }
    __syncthreads();
    for (int i = t; i < cnt; i += 256)
        col[cbase + i] = col_lds[i];
}

// ---------------- grouped fused aggregation, H=4: 16 lanes/node, 4 nodes/wave,
// uint4 gathers (1 KB/wave-inst), LDS p/soff exchange, software-pipelined
// col/as prefetch across chunks.
template<bool DOELU>
__global__ __launch_bounds__(256) void agg4g_kernel(
    const int* __restrict__ rowp, const int* __restrict__ col,
    const float* __restrict__ as_, const float* __restrict__ ad_,
    const u16* __restrict__ Hb16, const float* __restrict__ bias,
    u16* __restrict__ outp16)
{
    __shared__ float pex[4 * 288];
    __shared__ u32   sex[4 * 64];
    const int tid = threadIdx.x;
    const int wv = tid >> 6;
    const int lane = tid & 63;
    const int g = lane >> 4;
    const int sub = lane & 15;
    const int H = sub >> 2;
    const int node = blockIdx.x * 16 + wv * 4 + g;

    const int start = rowp[node];
    const int end   = rowp[node + 1];
    const float4 ad4 = ((const float4*)ad_)[node];
    const float4* as4 = (const float4*)as_;
    float* pb = &pex[wv * 288 + g * 68];
    u32*   sb = &sex[wv * 64 + g * 16];
    const char* hbase = (const char*)Hb16 + sub * 16;

    float m0 = -1e30f, m1 = -1e30f, m2 = -1e30f, m3 = -1e30f;
    float d0 = 0.f, d1 = 0.f, d2 = 0.f, d3 = 0.f;
    float a[8];
    #pragma unroll
    for (int i = 0; i < 8; i++) a[i] = 0.f;

    // prefetch chunk 0
    bool valid = (start + sub) < end;
    int s = valid ? col[start + sub] : 0;
    float4 av = as4[s];

    for (int j0 = start; j0 < end; j0 += 16) {
        // prefetch next chunk's col + as row (overlaps with this chunk's work)
        const int jn = j0 + 16 + sub;
        const bool vnext = (jn < end);
        const int snext = vnext ? col[jn] : 0;
        const float4 avn = as4[snext];

        float l0 = valid ? leaky(av.x + ad4.x) : -1e30f;
        float l1 = valid ? leaky(av.y + ad4.y) : -1e30f;
        float l2 = valid ? leaky(av.z + ad4.z) : -1e30f;
        float l3 = valid ? leaky(av.w + ad4.w) : -1e30f;
        float c0 = l0, c1 = l1, c2 = l2, c3 = l3;
        #pragma unroll
        for (int off = 8; off; off >>= 1) {
            c0 = fmaxf(c0, __shfl_xor(c0, off, 16));
            c1 = fmaxf(c1, __shfl_xor(c1, off, 16));
            c2 = fmaxf(c2, __shfl_xor(c2, off, 16));
            c3 = fmaxf(c3, __shfl_xor(c3, off, 16));
        }
        const float n0 = fmaxf(m0, c0), n1 = fmaxf(m1, c1);
        const float n2 = fmaxf(m2, c2), n3 = fmaxf(m3, c3);
        const float s0 = __expf(m0 - n0), s1 = __expf(m1 - n1);
        const float s2 = __expf(m2 - n2), s3 = __expf(m3 - n3);
        float p0 = valid ? __expf(l0 - n0) : 0.f;
        float p1 = valid ? __expf(l1 - n1) : 0.f;
        float p2 = valid ? __expf(l2 - n2) : 0.f;
        float p3 = valid ? __expf(l3 - n3) : 0.f;
        float q0 = p0, q1 = p1, q2 = p2, q3 = p3;
        #pragma unroll
        for (int off = 8; off; off >>= 1) {
            q0 += __shfl_xor(q0, off, 16);
            q1 += __shfl_xor(q1, off, 16);
            q2 += __shfl_xor(q2, off, 16);
            q3 += __shfl_xor(q3, off, 16);
        }
        d0 = d0 * s0 + q0; d1 = d1 * s1 + q1;
        d2 = d2 * s2 + q2; d3 = d3 * s3 + q3;
        m0 = n0; m1 = n1; m2 = n2; m3 = n3;
        const float scH = (H == 0) ? s0 : (H == 1) ? s1 : (H == 2) ? s2 : s3;
        #pragma unroll
        for (int i = 0; i < 8; i++) a[i] *= scH;
        pb[sub * 4 + 0] = p0; pb[sub * 4 + 1] = p1;
        pb[sub * 4 + 2] = p2; pb[sub * 4 + 3] = p3;
        sb[sub] = (u32)s << 8;
        u32 so[16]; float pi[16];
        #pragma unroll
        for (int i = 0; i < 16; i++) { so[i] = sb[i]; pi[i] = pb[i * 4 + H]; }
        #pragma unroll
        for (int i = 0; i < 16; i++) {
            const uint4 w = *(const uint4*)(hbase + so[i]);
            a[0] += pi[i] * bf_lo(w.x); a[1] += pi[i] * bf_hi(w.x);
            a[2] += pi[i] * bf_lo(w.y); a[3] += pi[i] * bf_hi(w.y);
            a[4] += pi[i] * bf_lo(w.z); a[5] += pi[i] * bf_hi(w.z);
            a[6] += pi[i] * bf_lo(w.w); a[7] += pi[i] * bf_hi(w.w);
        }
        s = snext; av = avn; valid = vnext;
    }
    const float denH = (H == 0) ? d0 : (H == 1) ? d1 : (H == 2) ? d2 : d3;
    const float r = 1.f / (denH + 1e-16f);
    const float4 b0 = ((const float4*)bias)[sub * 2];
    const float4 b1 = ((const float4*)bias)[sub * 2 + 1];
    float v[8];
    v[0] = a[0] * r + b0.x; v[1] = a[1] * r + b0.y;
    v[2] = a[2] * r + b0.z; v[3] = a[3] * r + b0.w;
    v[4] = a[4] * r + b1.x; v[5] = a[5] * r + b1.y;
    v[6] = a[6] * r + b1.z; v[7] = a[7] * r + b1.w;
    if (DOELU) {
        #pragma unroll
        for (int i = 0; i < 8; i++) v[i] = v[i] > 0.f ? v[i] : (__expf(v[i]) - 1.f);
    }
    uint4 o;
    o.x = (u32)f2bf(v[0]) | ((u32)f2bf(v[1]) << 16);
    o.y = (u32)f2bf(v[2]) | ((u32)f2bf(v[3]) << 16);
    o.z = (u32)f2bf(v[4]) | ((u32)f2bf(v[5]) << 16);
    o.w = (u32)f2bf(v[6]) | ((u32)f2bf(v[7]) << 16);
    *(uint4*)(outp16 + (size_t)node * 128 + sub * 8) = o;
}

// ---------------- H=1 (F=32): 32 lanes/node, pipelined col/as prefetch.
__global__ __launch_bounds__(256) void agg1_kernel(
    const int* __restrict__ rowp, const int* __restrict__ col,
    const float* __restrict__ as_, const float* __restrict__ ad_,
    const u16* __restrict__ Hb16, const float* __restrict__ bias,
    float* __restrict__ outp)
{
    const int t = threadIdx.x;
    const int lane = t & 31;
    const int node = blockIdx.x * 8 + (t >> 5);

    const int start = rowp[node];
    const int end   = rowp[node + 1];
    const float adv = ad_[node];
    const char* hbase = (const char*)Hb16 + lane * 2;
    const float bvv = bias[lane];

    float m = -1e30f, den = 0.f, acc = 0.f;
    bool valid = (start + lane) < end;
    int s = valid ? col[start + lane] : 0;
    float asv = as_[s];

    for (int j0 = start; j0 < end; j0 += 32) {
        const int jn = j0 + 32 + lane;
        const bool vnext = (jn < end);
        const int snext = vnext ? col[jn] : 0;
        const float asn = as_[snext];

        const float lg = valid ? leaky(asv + adv) : -1e30f;
        float cm = lg;
        #pragma unroll
        for (int off = 16; off; off >>= 1) cm = fmaxf(cm, __shfl_xor(cm, off, 32));
        const float mnew = fmaxf(m, cm);
        const float sc = __expf(m - mnew);
        acc *= sc; den *= sc; m = mnew;
        const float p = valid ? __expf(lg - m) : 0.f;
        float ps = p;
        #pragma unroll
        for (int off = 16; off; off >>= 1) ps += __shfl_xor(ps, off, 32);
        den += ps;
        const int soff = s << 6;
        int so[32]; float pi[32];
        #pragma unroll
        for (int i = 0; i < 32; i++) {
            so[i] = __shfl(soff, i, 32);
            pi[i] = __shfl(p, i, 32);
        }
        #pragma unroll
        for (int i = 0; i < 32; i++)
            acc += pi[i] * bf_lo((u32)*(const u16*)(hbase + so[i]));
        s = snext; asv = asn; valid = vnext;
    }
    outp[(size_t)node * 32 + lane] = acc / (den + 1e-16f) + bvv;
}

extern "C" void kernel_launch(void* const* d_in, const int* in_sizes, int n_in,
                              void* d_out, int out_size, void* d_ws, size_t ws_size,
                              hipStream_t stream)
{
    const float* x   = (const float*)d_in[0];
    const int*   ei  = (const int*)d_in[1];
    const float* W1  = (const float*)d_in[2];
    const float* as1 = (const float*)d_in[3];
    const float* ad1 = (const float*)d_in[4];
    const float* b1  = (const float*)d_in[5];
    const float* W2  = (const float*)d_in[6];
    const float* as2 = (const float*)d_in[7];
    const float* ad2 = (const float*)d_in[8];
    const float* b2  = (const float*)d_in[9];
    const float* W3  = (const float*)d_in[10];
    const float* as3 = (const float*)d_in[11];
    const float* ad3 = (const float*)d_in[12];
    const float* b3  = (const float*)d_in[13];
    float* outp = (float*)d_out;

    char* ws = (char*)d_ws;
    u16*   hb16  = (u16*)(ws);                    // N*128 bf16 = 25.6 MB (gather source)
    u16*   xb16  = (u16*)(ws + 25700000);         // N*128 bf16 = 25.6 MB (layer input)
    u16*   h3b16 = (u16*)(ws + 51400000);         // N*32 bf16 = 6.4 MB
    float* asb   = (float*)(ws + 57900000);       // N*4 f32
    float* adb   = (float*)(ws + 59500000);       // N*4 f32
    int*   rowp  = (int*)(ws + 61100000);         // N+1 ints
    int*   col   = (int*)(ws + 61600000);         // ET ints = 6.8 MB
    u32*   pairs = (u32*)(ws + 68400032);         // NBUCK*BCAP u32 = 11.2 MB
    int*   gcur  = (int*)(ws + 79700000);         // NBUCK ints (counts after fill)
    int*   bbase = (int*)(ws + 79704096);         // NBUCK+1 ints
    u16*   wt1   = (u16*)(ws + 79710000);         // 128x128 bf16 = 32 KB
    u16*   wt2   = (u16*)(ws + 79750000);         // 32 KB
    u16*   wt3   = (u16*)(ws + 79790000);         // 8 KB -> ~79.8 MB total

    const dim3 B(256);
    const int gG = (NN + 63) / 64;   // 1563

    // ---------------- one-time: W prep + bucketed CSR build
    wprep_kernel<<<144, B, 0, stream>>>(W1, W2, W3, wt1, wt2, wt3);
    hipMemsetAsync(gcur, 0, NBUCK * 4, stream);
    bin_fill_kernel<<<G_FILL, B, 0, stream>>>(ei, gcur, pairs);
    bscan_kernel<<<1, dim3(1024), 0, stream>>>(gcur, bbase, rowp);
    bucket_csr_kernel<<<NBUCK, B, 0, stream>>>(pairs, gcur, bbase, rowp, col);

    // ---------------- layer 1 (H=4)
    gemm_mfma<128, false><<<gG, B, 0, stream>>>(x, wt1, as1, ad1, hb16, asb, adb);
    agg4g_kernel<true><<<NN / 16, B, 0, stream>>>(rowp, col, asb, adb, hb16, b1, xb16);

    // ---------------- layer 2 (H=4)
    gemm_mfma<128, true><<<gG, B, 0, stream>>>(xb16, wt2, as2, ad2, hb16, asb, adb);
    agg4g_kernel<true><<<NN / 16, B, 0, stream>>>(rowp, col, asb, adb, hb16, b2, xb16);

    // ---------------- layer 3 (H=1, C=32)
    gemm_mfma<32, true><<<gG, B, 0, stream>>>(xb16, wt3, as3, ad3, h3b16, asb, adb);
    agg1_kernel<<<NN / 8, B, 0, stream>>>(rowp, col, asb, adb, h3b16, b3, outp);
}